// Round 1
// baseline (193.996 us; speedup 1.0000x reference)
//
#include <hip/hip_runtime.h>

// TT embedding lookup, fused single-kernel version.
// P=(216,216,216), Q=(2,4,2), R=(128,128), tables=2, batch=1024.
// core0: [2,216,256]   (A row:  [Q0=2][R0=128])
// core1: [2,216,65536] (Bm row: [R0=128][S=512], S = q1*128 + r1)
// core2: [2,216,256]   (C row:  [R1=128][Q2=2])
// out:   [2,1024,16]
//
// Grid (432 groups, 4 q-quarters) x 128 threads (2 waves = r-halves).
// Each block self-serves its lookup list: scans its table's 1024 indices
// (16 KB, L2-resident), decodes i0/i1/i2 with u32 magic division, and
// collects matches (i1 == group) into LDS. No prep kernel, no workspace.
//
// FMA loop processes rr in pairs: one ds_read_b128 broadcast delivers
// (A[0][r],A[1][r],A[0][r+1],A[1][r+1]) -> halves LDS issue vs b64.
// Epilogue split across both waves (l parity) after both dump partials.

#define CAP 128   // max lookups per (table,i1) group; Binomial(1024,1/216) ~ mean 4.74

__global__ __launch_bounds__(128) void tt_fused(
    const int* __restrict__ idx32,
    const float* __restrict__ c0,
    const float* __restrict__ c1,
    const float* __restrict__ c2,
    float* __restrict__ out)
{
    const int g     = blockIdx.x;      // group id [0,432) = table*216 + i1
    const int q     = blockIdx.y;      // s-quarter {0..3} == q1
    const int table = g / 216;
    const int i1    = g - table * 216;

    const int tid = threadIdx.x;
    const int rh  = tid >> 6;          // r-half: wave0 r<64, wave1 r>=64
    const int tl  = tid & 63;

    // 16 KB LDS, dual-purpose:
    //   [0,2048) floats: A staging ([l][2r+q0] interleave) during FMA loop
    //   [0,4096) floats: both waves' partial accumulators during combine
    __shared__ float lds[4096];
    __shared__ int s_id[CAP];
    __shared__ int s_aux[CAP];         // (i0<<16)|i2
    __shared__ int s_cnt;

    if (tid == 0) s_cnt = 0;
    __syncthreads();

    // int64-vs-int32 buffer detection (values < 2^31 => odd words zero in LE int64)
    const bool is64 = (idx32[1] == 0) & (idx32[3] == 0) &
                      (idx32[5] == 0) & (idx32[7] == 0);

    // scan this table's 1024 indices; collect matches (unordered is fine:
    // each lookup writes only its own output row)
    for (int j = tid; j < 1024; j += 128) {
        const int id = (table << 10) + j;
        const unsigned idx = is64 ? (unsigned)((const long long*)idx32)[id]
                                  : (unsigned)idx32[id];
        const unsigned i0  = idx / 46656u;           // compiler magic-mul (idx < 2^24)
        const unsigned rem = idx - i0 * 46656u;
        const unsigned bi1 = rem / 216u;
        if ((int)bi1 == i1) {
            const unsigned i2 = rem - bi1 * 216u;
            const int pos = atomicAdd(&s_cnt, 1);
            if (pos < CAP) {
                s_id[pos]  = id;
                s_aux[pos] = (int)((i0 << 16) | i2);
            }
        }
    }
    __syncthreads();
    const int m = min(s_cnt, CAP);
    if (m == 0) return;

    float2*       lds2 = (float2*)lds;
    const float4* lds4 = (const float4*)lds;

    // lane owns cols s = 128*q + 2*tl (+1); float2 index into row: r*256 + 64q + tl
    const float2* b2 = (const float2*)(c1 + ((size_t)g << 16))
                       + (size_t)rh * 64 * 256 + (q * 64 + tl);
    const float* c0t = c0 + (size_t)table * 216 * 256;

    for (int base = 0; base < m; base += 8) {
        const int cl = min(8, m - base);
        __syncthreads();               // previous pass's LDS reads done

        // stage A: coalesced global read, transposed LDS store (stride-2, 4-way = cheap)
        for (int l = 0; l < cl; ++l) {
            const float* ar = c0t + (size_t)(s_aux[base + l] >> 16) * 256;
#pragma unroll
            for (int k = 0; k < 2; ++k) {
                const int e = tid + 128 * k;                 // e = q0*128 + r
                lds[l * 256 + 2 * (e & 127) + (e >> 7)] = ar[e];
            }
        }
        __syncthreads();

        float2 acc[8][2];
#pragma unroll
        for (int l = 0; l < 8; ++l) {
            acc[l][0] = make_float2(0.f, 0.f);
            acc[l][1] = make_float2(0.f, 0.f);
        }

        // paired-rr FMA loop: 2 global float2 loads + 8 b128 broadcast reads
        // + 64 fmac per iteration. unroll 8 -> 16 B-loads in flight.
#pragma unroll 8
        for (int rr2 = 0; rr2 < 32; ++rr2) {
            const float2 bv0 = b2[(size_t)(2 * rr2) * 256];
            const float2 bv1 = b2[(size_t)(2 * rr2 + 1) * 256];
            const int rhalf = rh * 32 + rr2;                 // rfull/2
#pragma unroll
            for (int l = 0; l < 8; ++l) {
                const float4 av = lds4[l * 64 + rhalf];
                // av = (A[0][r], A[1][r], A[0][r+1], A[1][r+1]); l>=cl rows are
                // garbage (stale LDS) but their outputs are gated below.
                acc[l][0].x += av.x * bv0.x; acc[l][0].y += av.x * bv0.y;
                acc[l][1].x += av.y * bv0.x; acc[l][1].y += av.y * bv0.y;
                acc[l][0].x += av.z * bv1.x; acc[l][0].y += av.z * bv1.y;
                acc[l][1].x += av.w * bv1.x; acc[l][1].y += av.w * bv1.y;
            }
        }

        // r-split combine: BOTH waves dump partials (A region dead now),
        // then epilogue is split across waves by l parity (balanced at any cl).
        __syncthreads();
#pragma unroll
        for (int l = 0; l < 8; ++l) {
            lds2[((rh * 8 + l) * 2 + 0) * 64 + tl] = acc[l][0];
            lds2[((rh * 8 + l) * 2 + 1) * 64 + tl] = acc[l][1];
        }
        __syncthreads();

#pragma unroll
        for (int ll = 0; ll < 4; ++ll) {
            const int l = 2 * ll + rh;
            if (l < cl) {
                const float2 u0 = lds2[((0 * 8 + l) * 2 + 0) * 64 + tl];
                const float2 u1 = lds2[((1 * 8 + l) * 2 + 0) * 64 + tl];
                const float2 v0 = lds2[((0 * 8 + l) * 2 + 1) * 64 + tl];
                const float2 v1 = lds2[((1 * 8 + l) * 2 + 1) * 64 + tl];
                const float a0x = u0.x + u1.x, a0y = u0.y + u1.y;
                const float a1x = v0.x + v1.x, a1y = v0.y + v1.y;
                // lane's r1 = 2*tl, 2*tl+1; C[r1][j] at crow[r1*2+j]
                const float* crow = c2 + (size_t)(table * 216 + (s_aux[base + l] & 0xffff)) * 256;
                const float4 cv = *(const float4*)(crow + 4 * tl);
                float p00 = a0x * cv.x + a0y * cv.z;
                float p01 = a0x * cv.y + a0y * cv.w;
                float p10 = a1x * cv.x + a1y * cv.z;
                float p11 = a1x * cv.y + a1y * cv.w;
#pragma unroll
                for (int mm = 32; mm >= 1; mm >>= 1) {
                    p00 += __shfl_xor(p00, mm);
                    p01 += __shfl_xor(p01, mm);
                    p10 += __shfl_xor(p10, mm);
                    p11 += __shfl_xor(p11, mm);
                }
                if (tl == 0) {
                    float* o = out + (size_t)s_id[base + l] * 16;
                    *(float2*)(o + q * 2)     = make_float2(p00, p01);  // q0=0
                    *(float2*)(o + 8 + q * 2) = make_float2(p10, p11);  // q0=1
                }
            }
        }
    }
}

extern "C" void kernel_launch(void* const* d_in, const int* in_sizes, int n_in,
                              void* d_out, int out_size, void* d_ws, size_t ws_size,
                              hipStream_t stream) {
    const int*   idx = (const int*)d_in[0];
    const float* c0  = (const float*)d_in[1];
    const float* c1  = (const float*)d_in[2];
    const float* c2  = (const float*)d_in[3];
    float* out = (float*)d_out;
    (void)d_ws; (void)ws_size; (void)in_sizes; (void)n_in; (void)out_size;

    tt_fused<<<dim3(432, 4), dim3(128), 0, stream>>>(idx, c0, c1, c2, out);
}

// Round 3
// 191.290 us; speedup vs baseline: 1.0141x; 1.0141x over previous
//
#include <hip/hip_runtime.h>

// TT embedding lookup, fused single-kernel (binning redone per block).
// P=(216,216,216), Q=(2,4,2), R=(128,128), tables=2, batch=1024.
// core0: [2,216,256]   (A row:  [Q0=2][R0=128])
// core1: [2,216,65536] (Bm row: [R0=128][S=512], S = q1*128 + r1)
// core2: [2,216,256]   (C row:  [R1=128][Q2=2])
// out:   [2,1024,16]
//
// Grid (432 groups, 4 q-quarters, 2 chunk-slots) x 128 threads (2 waves =
// r-halves) -> 3456 blocks, LDS 8.6 KB, ~27 waves/CU for latency hiding.
// [Round-1 lesson: 1728 blocks x 17.9 KB LDS = Occupancy 26% -> 68 us.]
//
// Each block re-scans its table's 1024 indices (8 KB, L2-resident) and
// builds its match list DETERMINISTICALLY: wave0, 16 ballot-steps of 64,
// matches placed in increasing-j order via popcount-prefix. This makes the
// cs=0 / cs=1 blocks of the same (g,q) see identical lists, so the chunk
// partition (cs*8, step 16) is exact.  [Round-2 lesson: atomicAdd ordering
// differs across blocks -> some lookups fell in neither block's chunks.]
//
// FMA loop processes rr in pairs: one ds_read_b128 broadcast delivers
// (A[0][r],A[1][r],A[0][r+1],A[1][r+1]) -> half the LDS issue of b64.

#define CAP 48   // Binomial(1024,1/216): mean 4.74, P(m>48) ~ 0

__global__ __launch_bounds__(128) void tt_fused(
    const int* __restrict__ idx32,
    const float* __restrict__ c0,
    const float* __restrict__ c1,
    const float* __restrict__ c2,
    float* __restrict__ out)
{
    const int g     = blockIdx.x;      // group id [0,432) = table*216 + i1
    const int q     = blockIdx.y;      // s-quarter {0..3} == q1
    const int cs    = blockIdx.z;      // chunk slot {0,1}
    const int table = g / 216;
    const int i1    = g - table * 216;

    const int tid = threadIdx.x;
    const int rh  = tid >> 6;          // r-half: wave0 r<64, wave1 r>=64
    const int tl  = tid & 63;

    // 8 KB LDS, dual-purpose: A staging ([l][2r+q0] interleave) during the
    // FMA loop; wave1's partial accumulators during the r-split combine.
    __shared__ float lds[2048];
    __shared__ int s_id[CAP];
    __shared__ int s_aux[CAP];         // (i0<<16)|i2
    __shared__ int s_cnt;

    if (tid < CAP) s_aux[tid] = 0;     // pad rows -> row 0 (in-bounds; gated)

    // int64-vs-int32 buffer detection (values < 2^31 => odd words zero in LE)
    const bool is64 = (idx32[1] == 0) & (idx32[3] == 0) &
                      (idx32[5] == 0) & (idx32[7] == 0);

    // deterministic scan: wave0 only, j ascending in 16 ballot-steps of 64.
    if (rh == 0) {
        int cnt = 0;
#pragma unroll 4
        for (int it = 0; it < 16; ++it) {
            const int j  = it * 64 + tl;
            const int id = (table << 10) + j;
            const unsigned idx = is64 ? (unsigned)((const long long*)idx32)[id]
                                      : (unsigned)idx32[id];
            const unsigned i0  = idx / 46656u;       // magic-mul (idx < 2^24)
            const unsigned rem = idx - i0 * 46656u;
            const unsigned bi1 = rem / 216u;
            const bool match = ((int)bi1 == i1);
            const unsigned long long mask = __ballot(match);
            if (match) {
                const int pos = cnt + __popcll(mask & ((1ull << tl) - 1ull));
                if (pos < CAP) {
                    const unsigned i2 = rem - bi1 * 216u;
                    s_id[pos]  = id;
                    s_aux[pos] = (int)((i0 << 16) | i2);
                }
            }
            cnt += (int)__popcll(mask);              // uniform across wave
        }
        if (tl == 0) s_cnt = cnt;
    }
    __syncthreads();
    const int m = min(s_cnt, CAP);
    if (m <= cs * 8) return;           // cs=1 idle for ~95% of groups

    float2*       lds2 = (float2*)lds;
    const float4* lds4 = (const float4*)lds;

    // lane owns cols s = 128*q + 2*tl (+1); float2 index into row: r*256+64q+tl
    const float2* b2 = (const float2*)(c1 + ((size_t)g << 16))
                       + (size_t)rh * 64 * 256 + (q * 64 + tl);
    const float* c0t = c0 + (size_t)table * 216 * 256;

    for (int base = cs * 8; base < m; base += 16) {
        const int cl = min(8, m - base);
        __syncthreads();               // previous pass's LDS reads done

        // stage A: blind 8 rows (pad -> row 0), coalesced global read,
        // transposed LDS store (stride-2 = 2-way = free)
#pragma unroll
        for (int l = 0; l < 8; ++l) {
            const float* ar = c0t + (size_t)(s_aux[base + l] >> 16) * 256;
#pragma unroll
            for (int k = 0; k < 2; ++k) {
                const int e = tid + 128 * k;             // e = q0*128 + r
                lds[l * 256 + 2 * (e & 127) + (e >> 7)] = ar[e];
            }
        }
        __syncthreads();

        float2 acc[8][2];
#pragma unroll
        for (int l = 0; l < 8; ++l) {
            acc[l][0] = make_float2(0.f, 0.f);
            acc[l][1] = make_float2(0.f, 0.f);
        }

        // paired-rr FMA loop: 2 global float2 loads + 8 b128 broadcasts
        // + 64 fmac per iteration; unroll 8 -> 16 B-loads in flight.
#pragma unroll 8
        for (int rr2 = 0; rr2 < 32; ++rr2) {
            const float2 bv0 = b2[(size_t)(2 * rr2) * 256];
            const float2 bv1 = b2[(size_t)(2 * rr2 + 1) * 256];
            const int rhalf = rh * 32 + rr2;             // rfull/2
#pragma unroll
            for (int l = 0; l < 8; ++l) {
                const float4 av = lds4[l * 64 + rhalf];
                // av = (A[0][r],A[1][r],A[0][r+1],A[1][r+1]); l>=cl rows are
                // row-0 data but their outputs are gated below.
                acc[l][0].x += av.x * bv0.x; acc[l][0].y += av.x * bv0.y;
                acc[l][1].x += av.y * bv0.x; acc[l][1].y += av.y * bv0.y;
                acc[l][0].x += av.z * bv1.x; acc[l][0].y += av.z * bv1.y;
                acc[l][1].x += av.w * bv1.x; acc[l][1].y += av.w * bv1.y;
            }
        }

        // r-split combine: wave1 -> LDS (A region dead now), wave0 adds.
        __syncthreads();
        if (rh == 1) {
#pragma unroll
            for (int l = 0; l < 8; ++l) {
                lds2[(l * 2 + 0) * 64 + tl] = acc[l][0];
                lds2[(l * 2 + 1) * 64 + tl] = acc[l][1];
            }
        }
        __syncthreads();

        if (rh == 0) {
#pragma unroll
            for (int l = 0; l < 8; ++l) {
                const float2 t0 = lds2[(l * 2 + 0) * 64 + tl];
                const float2 t1 = lds2[(l * 2 + 1) * 64 + tl];
                const float a0x = acc[l][0].x + t0.x, a0y = acc[l][0].y + t0.y;
                const float a1x = acc[l][1].x + t1.x, a1y = acc[l][1].y + t1.y;
                if (l < cl) {
                    // lane's r1 = 2*tl, 2*tl+1; C[r1][j] at crow[r1*2+j]
                    const float* crow =
                        c2 + (size_t)(table * 216 + (s_aux[base + l] & 0xffff)) * 256;
                    const float4 cv = *(const float4*)(crow + 4 * tl);
                    float p00 = a0x * cv.x + a0y * cv.z;
                    float p01 = a0x * cv.y + a0y * cv.w;
                    float p10 = a1x * cv.x + a1y * cv.z;
                    float p11 = a1x * cv.y + a1y * cv.w;
#pragma unroll
                    for (int mm = 32; mm >= 1; mm >>= 1) {
                        p00 += __shfl_xor(p00, mm);
                        p01 += __shfl_xor(p01, mm);
                        p10 += __shfl_xor(p10, mm);
                        p11 += __shfl_xor(p11, mm);
                    }
                    if (tl == 0) {
                        float* o = out + (size_t)s_id[base + l] * 16;
                        *(float2*)(o + q * 2)     = make_float2(p00, p01);  // q0=0
                        *(float2*)(o + 8 + q * 2) = make_float2(p10, p11);  // q0=1
                    }
                }
            }
        }
    }
}

extern "C" void kernel_launch(void* const* d_in, const int* in_sizes, int n_in,
                              void* d_out, int out_size, void* d_ws, size_t ws_size,
                              hipStream_t stream) {
    const int*   idx = (const int*)d_in[0];
    const float* c0  = (const float*)d_in[1];
    const float* c1  = (const float*)d_in[2];
    const float* c2  = (const float*)d_in[3];
    float* out = (float*)d_out;
    (void)d_ws; (void)ws_size; (void)in_sizes; (void)n_in; (void)out_size;

    tt_fused<<<dim3(432, 4, 2), dim3(128), 0, stream>>>(idx, c0, c1, c2, out);
}